// Round 3
// baseline (751.816 us; speedup 1.0000x reference)
//
#include <hip/hip_runtime.h>
#include <hip/hip_cooperative_groups.h>
#include <math.h>

namespace cg = cooperative_groups;

#define CC    8
#define TFN   512
#define TGN   2048
#define HN    64
#define NITER 7
#define NBLK  256      // 32 blocks per condition
#define NTHR  512
#define RPB   16       // grn/AS rows per block
#define RPP   4        // rows staged per pass (32 KB LDS)

// padded LDS index: +1 float per 16 -> ds_read_b128 conflict-free (17L mod 32 bijective)
__device__ __forceinline__ int PW(int j) { return j + (j >> 4); }

__global__ __launch_bounds__(NTHR) void fused_kernel(
    const float* __restrict__ z, const float* __restrict__ grn,
    const int* __restrict__ tf,
    const float* __restrict__ wz, const float* __restrict__ bz,
    const float* __restrict__ w1, const float* __restrict__ b1,
    const float* __restrict__ w2, const float* __restrict__ b2,
    float* __restrict__ out,
    float* __restrict__ wbA, float* __restrict__ w2bA,
    float* __restrict__ wbB, float* __restrict__ w2bB)
{
    cg::grid_group grid = cg::this_grid();

    __shared__ float rows[RPP][TGN];              // 32 KB staging
    __shared__ int   tfs[TFN];                    // 2 KB
    __shared__ float wl[TFN + TFN/16];            // padded w   (2.125 KB)
    __shared__ float w2l[TFN + TFN/16];           // padded w2
    __shared__ float yloc[RPB][2];
    __shared__ float red[RPP][8][2];
    __shared__ float sv1[HN], su1[HN], sb1[HN], sw20[HN], sw21[HN], sb2[2];

    const int b = blockIdx.x;
    const int c = b >> 5;                 // condition
    const int rowbase = (b & 31) * RPB;   // first TF-row of this block
    const int t = threadIdx.x;
    const int myrow = t >> 5;             // 0..15  (32 threads per AS row)
    const int colb  = (t & 31) * 16;      // 16-col slice in TF space

    // ---- tf indices (clamped) ----
    for (int k = t; k < TFN; k += NTHR) {
        int v = tf[c * TFN + k];
        tfs[k] = v < 0 ? 0 : (v >= TGN ? TGN - 1 : v);
    }
    // ---- epi weights: v1 = w1@wz, u1 = w1@bz (threads 0..63) ----
    if (t < HN) {
        float a = 0.f, bb = 0.f;
        const float4* w14 = (const float4*)(w1 + t * HN);
        const float4* wz4 = (const float4*)wz;
        const float4* bz4 = (const float4*)bz;
#pragma unroll
        for (int h4 = 0; h4 < HN / 4; ++h4) {
            float4 w = w14[h4], a4 = wz4[h4], b4 = bz4[h4];
            a  += w.x * a4.x + w.y * a4.y + w.z * a4.z + w.w * a4.w;
            bb += w.x * b4.x + w.y * b4.y + w.z * b4.z + w.w * b4.w;
        }
        sv1[t] = a; su1[t] = bb;
        sb1[t] = b1[t]; sw20[t] = w2[t]; sw21[t] = w2[HN + t];
        if (t < 2) sb2[t] = b2[t];
    }

    // ---- my z slice (cols 4t..4t+3 of condition c) ----
    const float4 zv = ((const float4*)(z + c * TGN))[t];

    // ---- stream grn rows: y = A z, y2 = A 1, AS slice -> registers ----
    float As[16];
    const float* gbase = grn + (size_t)(c * TFN + rowbase) * TGN;
    const int wave = t >> 6, lane = t & 63;

    for (int p = 0; p < RPB / RPP; ++p) {
        float4 v[RPP];
#pragma unroll
        for (int r = 0; r < RPP; ++r)
            v[r] = ((const float4*)(gbase + (size_t)(p * RPP + r) * TGN))[t];
        float py[RPP], ps[RPP];
#pragma unroll
        for (int r = 0; r < RPP; ++r) {
            ((float4*)rows[r])[t] = v[r];
            py[r] = v[r].x * zv.x + v[r].y * zv.y + v[r].z * zv.z + v[r].w * zv.w;
            ps[r] = v[r].x + v[r].y + v[r].z + v[r].w;
        }
#pragma unroll
        for (int r = 0; r < RPP; ++r)
            for (int off = 32; off > 0; off >>= 1) {
                py[r] += __shfl_down(py[r], off);
                ps[r] += __shfl_down(ps[r], off);
            }
        if (lane == 0) {
#pragma unroll
            for (int r = 0; r < RPP; ++r) { red[r][wave][0] = py[r]; red[r][wave][1] = ps[r]; }
        }
        __syncthreads();
        if (t < RPP * 2) {                       // finalize y for this pass's rows
            int r = t >> 1, vv = t & 1;
            float s = 0.f;
#pragma unroll
            for (int w = 0; w < 8; ++w) s += red[r][w][vv];
            yloc[p * RPP + r][vv] = s;
            int grow = c * TFN + rowbase + p * RPP + r;   // w0 = y
            if (vv) w2bA[grow] = s; else wbA[grow] = s;
        }
        if ((myrow >> 2) == p) {                 // gather AS slice for my row
            int lr = myrow & 3;
#pragma unroll
            for (int i = 0; i < 16; ++i) As[i] = rows[lr][tfs[colb + i]];
        }
        __syncthreads();
    }

    __threadfence();
    grid.sync();
    __threadfence();

    // ---- Neumann iterations: w_{k+1} = y + A_S w_k  (dual RHS) ----
    for (int it = 0; it < NITER; ++it) {
        const float* wi  = (it & 1) ? wbB  : wbA;
        const float* w2i = (it & 1) ? w2bB : w2bA;
        float* wo  = (it & 1) ? wbA  : wbB;
        float* w2o = (it & 1) ? w2bA : w2bB;

        wl[PW(t)]  = wi[c * TFN + t];
        w2l[PW(t)] = w2i[c * TFN + t];
        __syncthreads();

        float a1 = 0.f, a2 = 0.f;
        const int base = colb + (colb >> 4);
#pragma unroll
        for (int i = 0; i < 16; ++i) {
            float a = As[i];
            a1 = fmaf(a, wl[base + i], a1);
            a2 = fmaf(a, w2l[base + i], a2);
        }
        for (int off = 16; off > 0; off >>= 1) {
            a1 += __shfl_down(a1, off);
            a2 += __shfl_down(a2, off);
        }
        if ((t & 31) == 0) {
            int grow = c * TFN + rowbase + myrow;
            wo[grow]  = yloc[myrow][0] + a1;
            w2o[grow] = yloc[myrow][1] + a2;
        }
        __syncthreads();
        __threadfence();
        grid.sync();
        __threadfence();
    }

    // ---- epilogue: 64 genes per block, 8 lanes per gene ----
    const float* wf  = (NITER & 1) ? wbB  : wbA;
    const float* w2f = (NITER & 1) ? w2bB : w2bA;
    wl[t]  = wf[c * TFN + t];
    w2l[t] = w2f[c * TFN + t];
    __syncthreads();

    const int g  = (b & 31) * 64 + (t >> 3);
    const int l8 = t & 7;
    int lo = 0, hi = TFN;
    while (lo < hi) { int m = (lo + hi) >> 1; if (tfs[m] < g) lo = m + 1; else hi = m; }
    float add = 0.f, add2 = 0.f;
    if (lo < TFN && tfs[lo] == g) { add = wl[lo]; add2 = w2l[lo]; }

    const float s  = z[c * TGN + g] + add;
    const float s2 = 1.f + add2;
    float a0 = 0.f, a1 = 0.f;
#pragma unroll
    for (int oo = 0; oo < 8; ++oo) {
        int o = l8 * 8 + oo;
        float pre = fmaf(s, sv1[o], fmaf(s2, su1[o], sb1[o]));
        float h = fmaxf(pre, 0.f);
        a0 = fmaf(sw20[o], h, a0);
        a1 = fmaf(sw21[o], h, a1);
    }
    for (int off = 4; off > 0; off >>= 1) {
        a0 += __shfl_down(a0, off);
        a1 += __shfl_down(a1, off);
    }
    if (l8 == 0) {
        float mu = a0 + sb2[0];
        float x  = a1 + sb2[1];
        float sp = fmaxf(x, 0.f) + log1pf(expf(-fabsf(x)));
        out[c * TGN + g]            = mu;
        out[CC * TGN + c * TGN + g] = sp + 1e-6f;
    }
}

extern "C" void kernel_launch(void* const* d_in, const int* in_sizes, int n_in,
                              void* d_out, int out_size, void* d_ws, size_t ws_size,
                              hipStream_t stream)
{
    const float* z   = (const float*)d_in[0];
    const float* grn = (const float*)d_in[1];
    const int*   tf  = (const int*)d_in[2];
    // d_in[3] = binary_tg (always arange, unused)
    const float* wz  = (const float*)d_in[4];
    const float* bz  = (const float*)d_in[5];
    const float* w1  = (const float*)d_in[6];
    const float* b1  = (const float*)d_in[7];
    const float* w2  = (const float*)d_in[8];
    const float* b2  = (const float*)d_in[9];
    float* out = (float*)d_out;

    float* wbA  = (float*)d_ws;              // 4 buffers x 4096 floats = 64 KB
    float* w2bA = wbA  + CC * TFN;
    float* wbB  = w2bA + CC * TFN;
    float* w2bB = wbB  + CC * TFN;

    void* args[] = { &z, &grn, &tf, &wz, &bz, &w1, &b1, &w2, &b2, &out,
                     &wbA, &w2bA, &wbB, &w2bB };
    hipLaunchCooperativeKernel((void*)fused_kernel, dim3(NBLK), dim3(NTHR),
                               args, 0, stream);
}

// Round 4
// 56.987 us; speedup vs baseline: 13.1928x; 13.1928x over previous
//
#include <hip/hip_runtime.h>
#include <math.h>

#define CC    8
#define TFN   512
#define TGN   2048
#define HN    64
#define NITER 7

// ---- bf16 helper (manual, RNE) ----
__device__ __forceinline__ unsigned short f2bf(float f) {
    unsigned int u = __float_as_uint(f);
    unsigned int r = (u + 0x7fffu + ((u >> 16) & 1u)) >> 16;
    return (unsigned short)r;
}

// ============================================================================
// K1: prep + baseline epilogue + flag zeroing.
//   blocks [0, 4096):   grn row (c,i): y, y2 (fp32), A_S row -> bf16, swizzled
//                       layout so K2's per-wave reads are 256B-contiguous.
//   blocks [4096,4160): baseline epi for all genes (s=z, s2=1)
//   block  4160:        zero the 2048-uint flags region
// ============================================================================
__global__ __launch_bounds__(256) void prep_kernel(
    const float* __restrict__ z, const float* __restrict__ grn,
    const int* __restrict__ tf,
    const float* __restrict__ wz, const float* __restrict__ bz,
    const float* __restrict__ w1, const float* __restrict__ b1,
    const float* __restrict__ w2, const float* __restrict__ b2,
    float* __restrict__ out,
    unsigned int* __restrict__ A2, float* __restrict__ y, float* __restrict__ y2,
    unsigned int* __restrict__ flags)
{
    const int b   = blockIdx.x;
    const int tid = threadIdx.x;

    if (b < CC * TFN) {
        // ---------------- grn row path ----------------
        __shared__ float row[TGN];
        __shared__ int   tfs[TFN];
        __shared__ float red[8];
        const int c = b >> 9;

        const float4* g4 = (const float4*)(grn + (size_t)b * TGN);
        const float4* z4 = (const float4*)(z + c * TGN);
        float4* r4 = (float4*)row;

        float accy = 0.f, accs = 0.f;
        for (int k = tid; k < TGN / 4; k += 256) {
            float4 g = g4[k];
            float4 zz = z4[k];
            r4[k] = g;
            accy += g.x * zz.x + g.y * zz.y + g.z * zz.z + g.w * zz.w;
            accs += g.x + g.y + g.z + g.w;
        }
        for (int k = tid; k < TFN; k += 256) {
            int t = tf[c * TFN + k];
            tfs[k] = t < 0 ? 0 : (t >= TGN ? TGN - 1 : t);
        }
        for (int off = 32; off > 0; off >>= 1) {
            accy += __shfl_down(accy, off);
            accs += __shfl_down(accs, off);
        }
        const int wave = tid >> 6, lane = tid & 63;
        if (lane == 0) { red[wave] = accy; red[4 + wave] = accs; }
        __syncthreads();
        if (tid == 0) {
            y[b]  = red[0] + red[1] + red[2] + red[3];
            y2[b] = red[4] + red[5] + red[6] + red[7];
        }
        // A_S row -> bf16, swizzled: i_row=b&511; q=i_row>>7; r=i_row&127
        // dword d (cols 2d,2d+1): off = (c*4+q)*32768 + (d>>3)*1024 + r*8 + (d&7)
        const int i_row = b & 511;
        const int q = i_row >> 7, r = i_row & 127;
        const size_t base = (size_t)(c * 4 + q) * 32768 + r * 8;
        const int d = tid;
        unsigned int lo = f2bf(row[tfs[2 * d]]);
        unsigned int hi = f2bf(row[tfs[2 * d + 1]]);
        A2[base + (size_t)(d >> 3) * 1024 + (d & 7)] = lo | (hi << 16);
    } else if (b < CC * TFN + 64) {
        // ---------------- baseline epi (all genes) ----------------
        __shared__ float sv1[HN], su1[HN], sb1[HN], sw20[HN], sw21[HN], sb2v[2];
        if (tid < HN) {
            float a = 0.f, bb = 0.f;
            const float4* w14 = (const float4*)(w1 + tid * HN);
            const float4* wz4 = (const float4*)wz;
            const float4* bz4 = (const float4*)bz;
#pragma unroll
            for (int h4 = 0; h4 < HN / 4; ++h4) {
                float4 w = w14[h4], a4 = wz4[h4], b4 = bz4[h4];
                a  += w.x * a4.x + w.y * a4.y + w.z * a4.z + w.w * a4.w;
                bb += w.x * b4.x + w.y * b4.y + w.z * b4.z + w.w * b4.w;
            }
            sv1[tid] = a; su1[tid] = bb;
            sb1[tid] = b1[tid]; sw20[tid] = w2[tid]; sw21[tid] = w2[HN + tid];
            if (tid < 2) sb2v[tid] = b2[tid];
        }
        __syncthreads();
        const int gid = (b - CC * TFN) * 256 + tid;   // 0..16383
        const float s = z[gid];
        float a0 = 0.f, a1 = 0.f;
#pragma unroll
        for (int o = 0; o < HN; ++o) {
            float pre = fmaf(s, sv1[o], su1[o] + sb1[o]);   // s2 = 1
            float h = fmaxf(pre, 0.f);
            a0 = fmaf(sw20[o], h, a0);
            a1 = fmaf(sw21[o], h, a1);
        }
        const float mu = a0 + sb2v[0];
        const float x  = a1 + sb2v[1];
        const float sp = fmaxf(x, 0.f) + log1pf(expf(-fabsf(x)));
        out[gid]            = mu;
        out[CC * TGN + gid] = sp + 1e-6f;
    } else {
        for (int k = tid; k < 2048; k += 256) flags[k] = 0u;
    }
}

// ============================================================================
// K2: Neumann solve (A_S bf16 in registers, 4 blocks/condition, soft barrier)
//     + TF-gene epilogue. Iteration 7 is local-only (no exchange needed).
// ============================================================================
__global__ __launch_bounds__(1024) void solve_kernel(
    const float* __restrict__ z, const int* __restrict__ tf,
    const float* __restrict__ wz, const float* __restrict__ bz,
    const float* __restrict__ w1, const float* __restrict__ b1,
    const float* __restrict__ w2, const float* __restrict__ b2,
    float* __restrict__ out,
    const unsigned int* __restrict__ A2,
    const float* __restrict__ y, const float* __restrict__ y2,
    float* __restrict__ wA, float* __restrict__ w2A,
    float* __restrict__ wB, float* __restrict__ w2B,
    unsigned int* __restrict__ flags)
{
    __shared__ float y_lds[2 * TFN];
    __shared__ float w_lds[2 * TFN];
    __shared__ float sv1[HN], su1[HN], sb1[HN], sw20[HN], sw21[HN], sb2v[2];
    __shared__ int   tfs_own[128];
    __shared__ float sS[128], sS2[128];

    const int b = blockIdx.x;
    const int c = b >> 2, q = b & 3;
    const int t = threadIdx.x;
    const int r = t >> 3, cb = t & 7;
    const int row0 = q * 128;

    // A slice -> registers: areg[i] holds cols {2(cb+8i), 2(cb+8i)+1} of row (row0+r)
    unsigned int areg[32];
    const unsigned int* Ab = A2 + (size_t)(c * 4 + q) * 32768 + r * 8 + cb;
#pragma unroll
    for (int i = 0; i < 32; ++i) areg[i] = Ab[(size_t)i * 1024];

    if (t < TFN) y_lds[t] = y[c * TFN + t];
    else         y_lds[t] = y2[c * TFN + (t - TFN)];
    if (t < HN) {
        float a = 0.f, bb = 0.f;
        const float4* w14 = (const float4*)(w1 + t * HN);
        const float4* wz4 = (const float4*)wz;
        const float4* bz4 = (const float4*)bz;
#pragma unroll
        for (int h4 = 0; h4 < HN / 4; ++h4) {
            float4 w = w14[h4], a4 = wz4[h4], b4 = bz4[h4];
            a  += w.x * a4.x + w.y * a4.y + w.z * a4.z + w.w * a4.w;
            bb += w.x * b4.x + w.y * b4.y + w.z * b4.z + w.w * b4.w;
        }
        sv1[t] = a; su1[t] = bb;
        sb1[t] = b1[t]; sw20[t] = w2[t]; sw21[t] = w2[HN + t];
        if (t < 2) sb2v[t] = b2[t];
    }
    if (t < 128) {
        int v = tf[c * TFN + row0 + t];
        tfs_own[t] = v < 0 ? 0 : (v >= TGN ? TGN - 1 : v);
    }
    __syncthreads();

    const float myY  = y_lds[row0 + r];
    const float myY2 = y_lds[TFN + row0 + r];

    float wv = 0.f, w2v = 0.f;   // own-chunk result (valid in cb==0 lanes)

    for (int it = 1; it <= NITER; ++it) {
        const float* src = (it == 1) ? y_lds : w_lds;
        float a1 = 0.f, a2 = 0.f;
#pragma unroll
        for (int i = 0; i < 32; ++i) {
            unsigned int ad = areg[i];
            float alo = __uint_as_float(ad << 16);
            float ahi = __uint_as_float(ad & 0xffff0000u);
            int j = 2 * (cb + 8 * i);
            a1 = fmaf(alo, src[j],           a1);
            a1 = fmaf(ahi, src[j + 1],       a1);
            a2 = fmaf(alo, src[TFN + j],     a2);
            a2 = fmaf(ahi, src[TFN + j + 1], a2);
        }
        a1 += __shfl_down(a1, 4, 8); a1 += __shfl_down(a1, 2, 8); a1 += __shfl_down(a1, 1, 8);
        a2 += __shfl_down(a2, 4, 8); a2 += __shfl_down(a2, 2, 8); a2 += __shfl_down(a2, 1, 8);
        if (cb == 0) { wv = myY + a1; w2v = myY2 + a2; }

        if (it < NITER) {
            float* wo  = (it & 1) ? wA  : wB;
            float* w2o = (it & 1) ? w2A : w2B;
            if (cb == 0) {
                wo[c * TFN + row0 + r]  = wv;
                w2o[c * TFN + row0 + r] = w2v;
            }
            __syncthreads();
            if (t == 0) {
                __threadfence();
                __hip_atomic_fetch_add(&flags[b * 64], 1u,
                                       __ATOMIC_RELEASE, __HIP_MEMORY_SCOPE_AGENT);
                for (int k = 0; k < 4; ++k) {
                    if (k == q) continue;
                    unsigned int* f = &flags[(c * 4 + k) * 64];
                    int guard = 0;
                    while (__hip_atomic_load(f, __ATOMIC_ACQUIRE,
                                             __HIP_MEMORY_SCOPE_AGENT) < (unsigned int)it) {
                        __builtin_amdgcn_s_sleep(2);
                        if (++guard > (1 << 22)) break;
                    }
                }
            }
            __syncthreads();
            const float* gw  = (it & 1) ? wA  : wB;
            const float* gw2 = (it & 1) ? w2A : w2B;
            if (t < TFN) w_lds[t] = gw[c * TFN + t];
            else         w_lds[t] = gw2[c * TFN + (t - TFN)];
            __syncthreads();
        }
    }

    // ---- TF-gene epilogue (own 128 rows) ----
    if (cb == 0) {
        int g = tfs_own[r];
        sS[r]  = z[c * TGN + g] + wv;
        sS2[r] = 1.f + w2v;
    }
    __syncthreads();
    const float s = sS[r], s2 = sS2[r];
    float a0 = 0.f, a1e = 0.f;
#pragma unroll
    for (int oo = 0; oo < 8; ++oo) {
        int o = cb * 8 + oo;
        float pre = fmaf(s, sv1[o], fmaf(s2, su1[o], sb1[o]));
        float h = fmaxf(pre, 0.f);
        a0  = fmaf(sw20[o], h, a0);
        a1e = fmaf(sw21[o], h, a1e);
    }
    a0  += __shfl_down(a0, 4, 8);  a0  += __shfl_down(a0, 2, 8);  a0  += __shfl_down(a0, 1, 8);
    a1e += __shfl_down(a1e, 4, 8); a1e += __shfl_down(a1e, 2, 8); a1e += __shfl_down(a1e, 1, 8);
    if (cb == 0) {
        int g = tfs_own[r];
        float mu = a0 + sb2v[0];
        float x  = a1e + sb2v[1];
        float sp = fmaxf(x, 0.f) + log1pf(expf(-fabsf(x)));
        out[c * TGN + g]            = mu;
        out[CC * TGN + c * TGN + g] = sp + 1e-6f;
    }
}

extern "C" void kernel_launch(void* const* d_in, const int* in_sizes, int n_in,
                              void* d_out, int out_size, void* d_ws, size_t ws_size,
                              hipStream_t stream)
{
    const float* z   = (const float*)d_in[0];
    const float* grn = (const float*)d_in[1];
    const int*   tf  = (const int*)d_in[2];
    const float* wz  = (const float*)d_in[4];
    const float* bz  = (const float*)d_in[5];
    const float* w1  = (const float*)d_in[6];
    const float* b1  = (const float*)d_in[7];
    const float* w2  = (const float*)d_in[8];
    const float* b2  = (const float*)d_in[9];
    float* out = (float*)d_out;

    char* ws = (char*)d_ws;
    unsigned int* A2 = (unsigned int*)ws;              // 4 MB (bf16 A_S, swizzled)
    float* y    = (float*)(ws + 4194304);
    float* y2   = (float*)(ws + 4210688);
    float* wA   = (float*)(ws + 4227072);
    float* w2A  = (float*)(ws + 4243456);
    float* wB   = (float*)(ws + 4259840);
    float* w2B  = (float*)(ws + 4276224);
    unsigned int* flags = (unsigned int*)(ws + 4292608);  // 8 KB

    prep_kernel<<<CC * TFN + 64 + 1, 256, 0, stream>>>(
        z, grn, tf, wz, bz, w1, b1, w2, b2, out, A2, y, y2, flags);

    solve_kernel<<<32, 1024, 0, stream>>>(
        z, tf, wz, bz, w1, b1, w2, b2, out, A2, y, y2, wA, w2A, wB, w2B, flags);
}

// Round 5
// 38.973 us; speedup vs baseline: 19.2904x; 1.4622x over previous
//
#include <hip/hip_runtime.h>
#include <math.h>

#define CC    8
#define TFN   512
#define TGN   2048
#define HN    64
#define NITER 4

// ---- bf16 helper (manual, RNE) ----
__device__ __forceinline__ unsigned short f2bf(float f) {
    unsigned int u = __float_as_uint(f);
    unsigned int r = (u + 0x7fffu + ((u >> 16) & 1u)) >> 16;
    return (unsigned short)r;
}

// ============================================================================
// K1: prep + baseline epilogue + flag zeroing.
//   blocks [0, 4096):   grn row (c,i): y, y2 (fp32), A_S row -> bf16, swizzled
//   blocks [4096,4160): baseline epi for all genes (s=z, s2=1)
//   block  4160:        zero the flags region
// ============================================================================
__global__ __launch_bounds__(256) void prep_kernel(
    const float* __restrict__ z, const float* __restrict__ grn,
    const int* __restrict__ tf,
    const float* __restrict__ wz, const float* __restrict__ bz,
    const float* __restrict__ w1, const float* __restrict__ b1,
    const float* __restrict__ w2, const float* __restrict__ b2,
    float* __restrict__ out,
    unsigned int* __restrict__ A2, float* __restrict__ y, float* __restrict__ y2,
    unsigned int* __restrict__ flags)
{
    const int b   = blockIdx.x;
    const int tid = threadIdx.x;

    if (b < CC * TFN) {
        // ---------------- grn row path ----------------
        __shared__ float row[TGN];
        __shared__ int   tfs[TFN];
        __shared__ float red[8];
        const int c = b >> 9;

        const float4* g4 = (const float4*)(grn + (size_t)b * TGN);
        const float4* z4 = (const float4*)(z + c * TGN);
        float4* r4 = (float4*)row;

        float accy = 0.f, accs = 0.f;
        for (int k = tid; k < TGN / 4; k += 256) {
            float4 g = g4[k];
            float4 zz = z4[k];
            r4[k] = g;
            accy += g.x * zz.x + g.y * zz.y + g.z * zz.z + g.w * zz.w;
            accs += g.x + g.y + g.z + g.w;
        }
        for (int k = tid; k < TFN; k += 256) {
            int t = tf[c * TFN + k];
            tfs[k] = t < 0 ? 0 : (t >= TGN ? TGN - 1 : t);
        }
        for (int off = 32; off > 0; off >>= 1) {
            accy += __shfl_down(accy, off);
            accs += __shfl_down(accs, off);
        }
        const int wave = tid >> 6, lane = tid & 63;
        if (lane == 0) { red[wave] = accy; red[4 + wave] = accs; }
        __syncthreads();
        if (tid == 0) {
            y[b]  = red[0] + red[1] + red[2] + red[3];
            y2[b] = red[4] + red[5] + red[6] + red[7];
        }
        // A_S row -> bf16, swizzled: i_row=b&511; q=i_row>>7; r=i_row&127
        // dword d (cols 2d,2d+1): off = (c*4+q)*32768 + (d>>3)*1024 + r*8 + (d&7)
        const int i_row = b & 511;
        const int q = i_row >> 7, r = i_row & 127;
        const size_t base = (size_t)(c * 4 + q) * 32768 + r * 8;
        const int d = tid;
        unsigned int lo = f2bf(row[tfs[2 * d]]);
        unsigned int hi = f2bf(row[tfs[2 * d + 1]]);
        A2[base + (size_t)(d >> 3) * 1024 + (d & 7)] = lo | (hi << 16);
    } else if (b < CC * TFN + 64) {
        // ---------------- baseline epi (all genes) ----------------
        __shared__ float sv1[HN], su1[HN], sb1[HN], sw20[HN], sw21[HN], sb2v[2];
        if (tid < HN) {
            float a = 0.f, bb = 0.f;
            const float4* w14 = (const float4*)(w1 + tid * HN);
            const float4* wz4 = (const float4*)wz;
            const float4* bz4 = (const float4*)bz;
#pragma unroll
            for (int h4 = 0; h4 < HN / 4; ++h4) {
                float4 w = w14[h4], a4 = wz4[h4], b4 = bz4[h4];
                a  += w.x * a4.x + w.y * a4.y + w.z * a4.z + w.w * a4.w;
                bb += w.x * b4.x + w.y * b4.y + w.z * b4.z + w.w * b4.w;
            }
            sv1[tid] = a; su1[tid] = bb;
            sb1[tid] = b1[tid]; sw20[tid] = w2[tid]; sw21[tid] = w2[HN + tid];
            if (tid < 2) sb2v[tid] = b2[tid];
        }
        __syncthreads();
        const int gid = (b - CC * TFN) * 256 + tid;   // 0..16383
        const float s = z[gid];
        float a0 = 0.f, a1 = 0.f;
#pragma unroll
        for (int o = 0; o < HN; ++o) {
            float pre = fmaf(s, sv1[o], su1[o] + sb1[o]);   // s2 = 1
            float h = fmaxf(pre, 0.f);
            a0 = fmaf(sw20[o], h, a0);
            a1 = fmaf(sw21[o], h, a1);
        }
        const float mu = a0 + sb2v[0];
        const float x  = a1 + sb2v[1];
        const float sp = fmaxf(x, 0.f) + log1pf(expf(-fabsf(x)));
        out[gid]            = mu;
        out[CC * TGN + gid] = sp + 1e-6f;
    } else {
        for (int k = tid; k < 2048; k += 256) flags[k] = 0u;
    }
}

// ============================================================================
// K2: Neumann solve (A_S bf16 in registers, 4 blocks/condition, soft barrier
// with relaxed-poll protocol) + TF-gene epilogue. NITER=4 -> 3 cross syncs.
// ============================================================================
__global__ __launch_bounds__(1024) void solve_kernel(
    const float* __restrict__ z, const int* __restrict__ tf,
    const float* __restrict__ wz, const float* __restrict__ bz,
    const float* __restrict__ w1, const float* __restrict__ b1,
    const float* __restrict__ w2, const float* __restrict__ b2,
    float* __restrict__ out,
    const unsigned int* __restrict__ A2,
    const float* __restrict__ y, const float* __restrict__ y2,
    float* __restrict__ wA, float* __restrict__ w2A,
    float* __restrict__ wB, float* __restrict__ w2B,
    unsigned int* __restrict__ flags)
{
    __shared__ float y_lds[2 * TFN];
    __shared__ float w_lds[2 * TFN];
    __shared__ float sv1[HN], su1[HN], sb1[HN], sw20[HN], sw21[HN], sb2v[2];
    __shared__ int   tfs_own[128];
    __shared__ float sS[128], sS2[128];

    const int b = blockIdx.x;
    const int c = b >> 2, q = b & 3;
    const int t = threadIdx.x;
    const int r = t >> 3, cb = t & 7;
    const int row0 = q * 128;

    // A slice -> registers: areg[i] holds cols {2(cb+8i), 2(cb+8i)+1} of row (row0+r)
    unsigned int areg[32];
    const unsigned int* Ab = A2 + (size_t)(c * 4 + q) * 32768 + r * 8 + cb;
#pragma unroll
    for (int i = 0; i < 32; ++i) areg[i] = Ab[(size_t)i * 1024];

    if (t < TFN) y_lds[t] = y[c * TFN + t];
    else         y_lds[t] = y2[c * TFN + (t - TFN)];
    if (t < HN) {
        float a = 0.f, bb = 0.f;
        const float4* w14 = (const float4*)(w1 + t * HN);
        const float4* wz4 = (const float4*)wz;
        const float4* bz4 = (const float4*)bz;
#pragma unroll
        for (int h4 = 0; h4 < HN / 4; ++h4) {
            float4 w = w14[h4], a4 = wz4[h4], b4 = bz4[h4];
            a  += w.x * a4.x + w.y * a4.y + w.z * a4.z + w.w * a4.w;
            bb += w.x * b4.x + w.y * b4.y + w.z * b4.z + w.w * b4.w;
        }
        sv1[t] = a; su1[t] = bb;
        sb1[t] = b1[t]; sw20[t] = w2[t]; sw21[t] = w2[HN + t];
        if (t < 2) sb2v[t] = b2[t];
    }
    if (t < 128) {
        int v = tf[c * TFN + row0 + t];
        tfs_own[t] = v < 0 ? 0 : (v >= TGN ? TGN - 1 : v);
    }
    __syncthreads();

    const float myY  = y_lds[row0 + r];
    const float myY2 = y_lds[TFN + row0 + r];

    float wv = 0.f, w2v = 0.f;   // own-chunk result (valid in cb==0 lanes)

    for (int it = 1; it <= NITER; ++it) {
        const float* src = (it == 1) ? y_lds : w_lds;
        float a1 = 0.f, a2 = 0.f;
#pragma unroll
        for (int i = 0; i < 32; ++i) {
            unsigned int ad = areg[i];
            float alo = __uint_as_float(ad << 16);
            float ahi = __uint_as_float(ad & 0xffff0000u);
            int j = 2 * (cb + 8 * i);
            a1 = fmaf(alo, src[j],           a1);
            a1 = fmaf(ahi, src[j + 1],       a1);
            a2 = fmaf(alo, src[TFN + j],     a2);
            a2 = fmaf(ahi, src[TFN + j + 1], a2);
        }
        a1 += __shfl_down(a1, 4, 8); a1 += __shfl_down(a1, 2, 8); a1 += __shfl_down(a1, 1, 8);
        a2 += __shfl_down(a2, 4, 8); a2 += __shfl_down(a2, 2, 8); a2 += __shfl_down(a2, 1, 8);
        if (cb == 0) { wv = myY + a1; w2v = myY2 + a2; }

        if (it < NITER) {
            float* wo  = (it & 1) ? wA  : wB;
            float* w2o = (it & 1) ? w2A : w2B;
            if (cb == 0) {
                wo[c * TFN + row0 + r]  = wv;
                w2o[c * TFN + row0 + r] = w2v;
            }
            __syncthreads();
            // soft barrier across the condition's 4 blocks:
            //  wave0 t==0: RELEASE-increment own flag (orders the stores above)
            //  waves 1/2/3 (t=64,128,192): poll one remote flag each, RELAXED
            //  (cheap, no per-poll cache invalidate) with periodic ACQUIRE
            //  fallback, then one final ACQUIRE load to invalidate caches.
            if (t == 0) {
                __hip_atomic_fetch_add(&flags[b * 64], 1u,
                                       __ATOMIC_RELEASE, __HIP_MEMORY_SCOPE_AGENT);
            } else if (t == 64 || t == 128 || t == 192) {
                int k = (t >> 6) - 1;
                k += (k >= q);   // map 0..2 onto the other three q's
                unsigned int* f = &flags[(c * 4 + k) * 64];
                int polls = 0;
                while (__hip_atomic_load(f, __ATOMIC_RELAXED,
                                         __HIP_MEMORY_SCOPE_AGENT) < (unsigned int)it) {
                    __builtin_amdgcn_s_sleep(2);
                    ++polls;
                    if ((polls & 31) == 0) {
                        if (__hip_atomic_load(f, __ATOMIC_ACQUIRE,
                                              __HIP_MEMORY_SCOPE_AGENT) >= (unsigned int)it)
                            break;
                    }
                    if (polls > (1 << 22)) break;
                }
                (void)__hip_atomic_load(f, __ATOMIC_ACQUIRE, __HIP_MEMORY_SCOPE_AGENT);
            }
            __syncthreads();
            const float* gw  = (it & 1) ? wA  : wB;
            const float* gw2 = (it & 1) ? w2A : w2B;
            if (t < TFN) w_lds[t] = gw[c * TFN + t];
            else         w_lds[t] = gw2[c * TFN + (t - TFN)];
            __syncthreads();
        }
    }

    // ---- TF-gene epilogue (own 128 rows) ----
    if (cb == 0) {
        int g = tfs_own[r];
        sS[r]  = z[c * TGN + g] + wv;
        sS2[r] = 1.f + w2v;
    }
    __syncthreads();
    const float s = sS[r], s2 = sS2[r];
    float a0 = 0.f, a1e = 0.f;
#pragma unroll
    for (int oo = 0; oo < 8; ++oo) {
        int o = cb * 8 + oo;
        float pre = fmaf(s, sv1[o], fmaf(s2, su1[o], sb1[o]));
        float h = fmaxf(pre, 0.f);
        a0  = fmaf(sw20[o], h, a0);
        a1e = fmaf(sw21[o], h, a1e);
    }
    a0  += __shfl_down(a0, 4, 8);  a0  += __shfl_down(a0, 2, 8);  a0  += __shfl_down(a0, 1, 8);
    a1e += __shfl_down(a1e, 4, 8); a1e += __shfl_down(a1e, 2, 8); a1e += __shfl_down(a1e, 1, 8);
    if (cb == 0) {
        int g = tfs_own[r];
        float mu = a0 + sb2v[0];
        float x  = a1e + sb2v[1];
        float sp = fmaxf(x, 0.f) + log1pf(expf(-fabsf(x)));
        out[c * TGN + g]            = mu;
        out[CC * TGN + c * TGN + g] = sp + 1e-6f;
    }
}

extern "C" void kernel_launch(void* const* d_in, const int* in_sizes, int n_in,
                              void* d_out, int out_size, void* d_ws, size_t ws_size,
                              hipStream_t stream)
{
    const float* z   = (const float*)d_in[0];
    const float* grn = (const float*)d_in[1];
    const int*   tf  = (const int*)d_in[2];
    const float* wz  = (const float*)d_in[4];
    const float* bz  = (const float*)d_in[5];
    const float* w1  = (const float*)d_in[6];
    const float* b1  = (const float*)d_in[7];
    const float* w2  = (const float*)d_in[8];
    const float* b2  = (const float*)d_in[9];
    float* out = (float*)d_out;

    char* ws = (char*)d_ws;
    unsigned int* A2 = (unsigned int*)ws;              // 4 MB (bf16 A_S, swizzled)
    float* y    = (float*)(ws + 4194304);
    float* y2   = (float*)(ws + 4210688);
    float* wA   = (float*)(ws + 4227072);
    float* w2A  = (float*)(ws + 4243456);
    float* wB   = (float*)(ws + 4259840);
    float* w2B  = (float*)(ws + 4276224);
    unsigned int* flags = (unsigned int*)(ws + 4292608);  // 8 KB

    prep_kernel<<<CC * TFN + 64 + 1, 256, 0, stream>>>(
        z, grn, tf, wz, bz, w1, b1, w2, b2, out, A2, y, y2, flags);

    solve_kernel<<<32, 1024, 0, stream>>>(
        z, tf, wz, bz, w1, b1, w2, b2, out, A2, y, y2, wA, w2A, wB, w2B, flags);
}

// Round 6
// 35.828 us; speedup vs baseline: 20.9842x; 1.0878x over previous
//
#include <hip/hip_runtime.h>
#include <math.h>

#define CC    8
#define TFN   512
#define TGN   2048
#define HN    64
#define NITER 4

// ---- bf16 helper (manual, RNE) ----
__device__ __forceinline__ unsigned short f2bf(float f) {
    unsigned int u = __float_as_uint(f);
    unsigned int r = (u + 0x7fffu + ((u >> 16) & 1u)) >> 16;
    return (unsigned short)r;
}

// ============================================================================
// K1: prep + baseline epilogue + flag zeroing.
//   blocks [0, 4096):   grn row (c,i): y, y2 (fp32), A_S row -> bf16, swizzled
//   blocks [4096,4160): baseline epi for all genes (s=z, s2=1)
//   block  4160:        zero the flags region (atomic, LLC-visible)
// ============================================================================
__global__ __launch_bounds__(256) void prep_kernel(
    const float* __restrict__ z, const float* __restrict__ grn,
    const int* __restrict__ tf,
    const float* __restrict__ wz, const float* __restrict__ bz,
    const float* __restrict__ w1, const float* __restrict__ b1,
    const float* __restrict__ w2, const float* __restrict__ b2,
    float* __restrict__ out,
    unsigned int* __restrict__ A2, float* __restrict__ y, float* __restrict__ y2,
    unsigned int* __restrict__ flags)
{
    const int b   = blockIdx.x;
    const int tid = threadIdx.x;

    if (b < CC * TFN) {
        // ---------------- grn row path ----------------
        __shared__ float row[TGN];
        __shared__ int   tfs[TFN];
        __shared__ float red[8];
        const int c = b >> 9;

        const float4* g4 = (const float4*)(grn + (size_t)b * TGN);
        const float4* z4 = (const float4*)(z + c * TGN);
        float4* r4 = (float4*)row;

        float accy = 0.f, accs = 0.f;
        for (int k = tid; k < TGN / 4; k += 256) {
            float4 g = g4[k];
            float4 zz = z4[k];
            r4[k] = g;
            accy += g.x * zz.x + g.y * zz.y + g.z * zz.z + g.w * zz.w;
            accs += g.x + g.y + g.z + g.w;
        }
        for (int k = tid; k < TFN; k += 256) {
            int t = tf[c * TFN + k];
            tfs[k] = t < 0 ? 0 : (t >= TGN ? TGN - 1 : t);
        }
        for (int off = 32; off > 0; off >>= 1) {
            accy += __shfl_down(accy, off);
            accs += __shfl_down(accs, off);
        }
        const int wave = tid >> 6, lane = tid & 63;
        if (lane == 0) { red[wave] = accy; red[4 + wave] = accs; }
        __syncthreads();
        if (tid == 0) {
            y[b]  = red[0] + red[1] + red[2] + red[3];
            y2[b] = red[4] + red[5] + red[6] + red[7];
        }
        // A_S row -> bf16, swizzled: i_row=b&511; q=i_row>>7; r=i_row&127
        // dword d (cols 2d,2d+1): off = (c*4+q)*32768 + (d>>3)*1024 + r*8 + (d&7)
        const int i_row = b & 511;
        const int q = i_row >> 7, r = i_row & 127;
        const size_t base = (size_t)(c * 4 + q) * 32768 + r * 8;
        const int d = tid;
        unsigned int lo = f2bf(row[tfs[2 * d]]);
        unsigned int hi = f2bf(row[tfs[2 * d + 1]]);
        A2[base + (size_t)(d >> 3) * 1024 + (d & 7)] = lo | (hi << 16);
    } else if (b < CC * TFN + 64) {
        // ---------------- baseline epi (all genes) ----------------
        __shared__ float sv1[HN], su1[HN], sb1[HN], sw20[HN], sw21[HN], sb2v[2];
        if (tid < HN) {
            float a = 0.f, bb = 0.f;
            const float4* w14 = (const float4*)(w1 + tid * HN);
            const float4* wz4 = (const float4*)wz;
            const float4* bz4 = (const float4*)bz;
#pragma unroll
            for (int h4 = 0; h4 < HN / 4; ++h4) {
                float4 w = w14[h4], a4 = wz4[h4], b4 = bz4[h4];
                a  += w.x * a4.x + w.y * a4.y + w.z * a4.z + w.w * a4.w;
                bb += w.x * b4.x + w.y * b4.y + w.z * b4.z + w.w * b4.w;
            }
            sv1[tid] = a; su1[tid] = bb;
            sb1[tid] = b1[tid]; sw20[tid] = w2[tid]; sw21[tid] = w2[HN + tid];
            if (tid < 2) sb2v[tid] = b2[tid];
        }
        __syncthreads();
        const int gid = (b - CC * TFN) * 256 + tid;   // 0..16383
        const float s = z[gid];
        float a0 = 0.f, a1 = 0.f;
#pragma unroll
        for (int o = 0; o < HN; ++o) {
            float pre = fmaf(s, sv1[o], su1[o] + sb1[o]);   // s2 = 1
            float h = fmaxf(pre, 0.f);
            a0 = fmaf(sw20[o], h, a0);
            a1 = fmaf(sw21[o], h, a1);
        }
        const float mu = a0 + sb2v[0];
        const float x  = a1 + sb2v[1];
        const float sp = fmaxf(x, 0.f) + log1pf(expf(-fabsf(x)));
        out[gid]            = mu;
        out[CC * TGN + gid] = sp + 1e-6f;
    } else {
        for (int k = tid; k < 2048; k += 256)
            __hip_atomic_store(&flags[k], 0u, __ATOMIC_RELAXED, __HIP_MEMORY_SCOPE_AGENT);
    }
}

// ============================================================================
// K2: Neumann solve (A_S bf16 in registers, 4 blocks/condition) + TF-gene epi.
// Cross-block exchange is ALL-ATOMIC at relaxed/agent scope: data published
// with atomic stores (LLC-resident), flag via fetch_add, poll via fetch_add(0)
// RMW (always reads true LLC value), data re-read with atomic loads.
// No acquire/release -> no L2 invalidate/writeback instructions anywhere.
// ============================================================================
__global__ __launch_bounds__(1024) void solve_kernel(
    const float* __restrict__ z, const int* __restrict__ tf,
    const float* __restrict__ wz, const float* __restrict__ bz,
    const float* __restrict__ w1, const float* __restrict__ b1,
    const float* __restrict__ w2, const float* __restrict__ b2,
    float* __restrict__ out,
    const unsigned int* __restrict__ A2,
    const float* __restrict__ y, const float* __restrict__ y2,
    float* __restrict__ wA, float* __restrict__ w2A,
    float* __restrict__ wB, float* __restrict__ w2B,
    unsigned int* __restrict__ flags)
{
    __shared__ float y_lds[2 * TFN];
    __shared__ float w_lds[2 * TFN];
    __shared__ float sv1[HN], su1[HN], sb1[HN], sw20[HN], sw21[HN], sb2v[2];
    __shared__ int   tfs_own[128];
    __shared__ float sS[128], sS2[128];

    const int b = blockIdx.x;
    const int c = b >> 2, q = b & 3;
    const int t = threadIdx.x;
    const int r = t >> 3, cb = t & 7;
    const int row0 = q * 128;

    // A slice -> registers: areg[i] holds cols {2(cb+8i), 2(cb+8i)+1} of row (row0+r)
    unsigned int areg[32];
    const unsigned int* Ab = A2 + (size_t)(c * 4 + q) * 32768 + r * 8 + cb;
#pragma unroll
    for (int i = 0; i < 32; ++i) areg[i] = Ab[(size_t)i * 1024];

    if (t < TFN) y_lds[t] = y[c * TFN + t];
    else         y_lds[t] = y2[c * TFN + (t - TFN)];
    if (t < HN) {
        float a = 0.f, bb = 0.f;
        const float4* w14 = (const float4*)(w1 + t * HN);
        const float4* wz4 = (const float4*)wz;
        const float4* bz4 = (const float4*)bz;
#pragma unroll
        for (int h4 = 0; h4 < HN / 4; ++h4) {
            float4 w = w14[h4], a4 = wz4[h4], b4 = bz4[h4];
            a  += w.x * a4.x + w.y * a4.y + w.z * a4.z + w.w * a4.w;
            bb += w.x * b4.x + w.y * b4.y + w.z * b4.z + w.w * b4.w;
        }
        sv1[t] = a; su1[t] = bb;
        sb1[t] = b1[t]; sw20[t] = w2[t]; sw21[t] = w2[HN + t];
        if (t < 2) sb2v[t] = b2[t];
    }
    if (t < 128) {
        int v = tf[c * TFN + row0 + t];
        tfs_own[t] = v < 0 ? 0 : (v >= TGN ? TGN - 1 : v);
    }
    __syncthreads();

    const float myY  = y_lds[row0 + r];
    const float myY2 = y_lds[TFN + row0 + r];

    float wv = 0.f, w2v = 0.f;   // own-chunk result (valid in cb==0 lanes)

    for (int it = 1; it <= NITER; ++it) {
        const float* src = (it == 1) ? y_lds : w_lds;
        float a1 = 0.f, a2 = 0.f;
#pragma unroll
        for (int i = 0; i < 32; ++i) {
            unsigned int ad = areg[i];
            float alo = __uint_as_float(ad << 16);
            float ahi = __uint_as_float(ad & 0xffff0000u);
            int j = 2 * (cb + 8 * i);
            a1 = fmaf(alo, src[j],           a1);
            a1 = fmaf(ahi, src[j + 1],       a1);
            a2 = fmaf(alo, src[TFN + j],     a2);
            a2 = fmaf(ahi, src[TFN + j + 1], a2);
        }
        a1 += __shfl_down(a1, 4, 8); a1 += __shfl_down(a1, 2, 8); a1 += __shfl_down(a1, 1, 8);
        a2 += __shfl_down(a2, 4, 8); a2 += __shfl_down(a2, 2, 8); a2 += __shfl_down(a2, 1, 8);
        if (cb == 0) { wv = myY + a1; w2v = myY2 + a2; }

        if (it < NITER) {
            float* wo  = (it & 1) ? wA  : wB;
            float* w2o = (it & 1) ? w2A : w2B;
            if (cb == 0) {
                // publish at the coherence point (no L2 involvement)
                __hip_atomic_store(&wo[c * TFN + row0 + r],  wv,
                                   __ATOMIC_RELAXED, __HIP_MEMORY_SCOPE_AGENT);
                __hip_atomic_store(&w2o[c * TFN + row0 + r], w2v,
                                   __ATOMIC_RELAXED, __HIP_MEMORY_SCOPE_AGENT);
            }
            __syncthreads();   // drains vmcnt -> stores completed at LLC
            if (t == 0) {
                __hip_atomic_fetch_add(&flags[b * 64], 1u,
                                       __ATOMIC_RELAXED, __HIP_MEMORY_SCOPE_AGENT);
            } else if (t == 64 || t == 128 || t == 192) {
                int k = (t >> 6) - 1;
                k += (k >= q);   // the other three q's
                unsigned int* f = &flags[(c * 4 + k) * 64];
                int polls = 0;
                // RMW poll: always reads the true LLC value (no staleness)
                while (__hip_atomic_fetch_add(f, 0u, __ATOMIC_RELAXED,
                                              __HIP_MEMORY_SCOPE_AGENT) < (unsigned int)it) {
                    __builtin_amdgcn_s_sleep(1);
                    if (++polls > (1 << 22)) break;
                }
            }
            __syncthreads();
            const float* gw  = (it & 1) ? wA  : wB;
            const float* gw2 = (it & 1) ? w2A : w2B;
            // atomic relaxed loads: fetch from LLC, bypass (possibly stale) L2
            if (t < TFN)
                w_lds[t] = __hip_atomic_load(&gw[c * TFN + t],
                                             __ATOMIC_RELAXED, __HIP_MEMORY_SCOPE_AGENT);
            else
                w_lds[t] = __hip_atomic_load(&gw2[c * TFN + (t - TFN)],
                                             __ATOMIC_RELAXED, __HIP_MEMORY_SCOPE_AGENT);
            __syncthreads();
        }
    }

    // ---- TF-gene epilogue (own 128 rows) ----
    if (cb == 0) {
        int g = tfs_own[r];
        sS[r]  = z[c * TGN + g] + wv;
        sS2[r] = 1.f + w2v;
    }
    __syncthreads();
    const float s = sS[r], s2 = sS2[r];
    float a0 = 0.f, a1e = 0.f;
#pragma unroll
    for (int oo = 0; oo < 8; ++oo) {
        int o = cb * 8 + oo;
        float pre = fmaf(s, sv1[o], fmaf(s2, su1[o], sb1[o]));
        float h = fmaxf(pre, 0.f);
        a0  = fmaf(sw20[o], h, a0);
        a1e = fmaf(sw21[o], h, a1e);
    }
    a0  += __shfl_down(a0, 4, 8);  a0  += __shfl_down(a0, 2, 8);  a0  += __shfl_down(a0, 1, 8);
    a1e += __shfl_down(a1e, 4, 8); a1e += __shfl_down(a1e, 2, 8); a1e += __shfl_down(a1e, 1, 8);
    if (cb == 0) {
        int g = tfs_own[r];
        float mu = a0 + sb2v[0];
        float x  = a1e + sb2v[1];
        float sp = fmaxf(x, 0.f) + log1pf(expf(-fabsf(x)));
        out[c * TGN + g]            = mu;
        out[CC * TGN + c * TGN + g] = sp + 1e-6f;
    }
}

extern "C" void kernel_launch(void* const* d_in, const int* in_sizes, int n_in,
                              void* d_out, int out_size, void* d_ws, size_t ws_size,
                              hipStream_t stream)
{
    const float* z   = (const float*)d_in[0];
    const float* grn = (const float*)d_in[1];
    const int*   tf  = (const int*)d_in[2];
    const float* wz  = (const float*)d_in[4];
    const float* bz  = (const float*)d_in[5];
    const float* w1  = (const float*)d_in[6];
    const float* b1  = (const float*)d_in[7];
    const float* w2  = (const float*)d_in[8];
    const float* b2  = (const float*)d_in[9];
    float* out = (float*)d_out;

    char* ws = (char*)d_ws;
    unsigned int* A2 = (unsigned int*)ws;              // 4 MB (bf16 A_S, swizzled)
    float* y    = (float*)(ws + 4194304);
    float* y2   = (float*)(ws + 4210688);
    float* wA   = (float*)(ws + 4227072);
    float* w2A  = (float*)(ws + 4243456);
    float* wB   = (float*)(ws + 4259840);
    float* w2B  = (float*)(ws + 4276224);
    unsigned int* flags = (unsigned int*)(ws + 4292608);  // 8 KB

    prep_kernel<<<CC * TFN + 64 + 1, 256, 0, stream>>>(
        z, grn, tf, wz, bz, w1, b1, w2, b2, out, A2, y, y2, flags);

    solve_kernel<<<32, 1024, 0, stream>>>(
        z, tf, wz, bz, w1, b1, w2, b2, out, A2, y, y2, wA, w2A, wB, w2B, flags);
}

// Round 7
// 34.491 us; speedup vs baseline: 21.7977x; 1.0388x over previous
//
#include <hip/hip_runtime.h>
#include <math.h>

#define CC    8
#define TFN   512
#define TGN   2048
#define HN    64
#define NITER 4

// ---- bf16 helper (manual, RNE) ----
__device__ __forceinline__ unsigned short f2bf(float f) {
    unsigned int u = __float_as_uint(f);
    unsigned int r = (u + 0x7fffu + ((u >> 16) & 1u)) >> 16;
    return (unsigned short)r;
}

// ============================================================================
// K1: prep + baseline epilogue + pair-buffer zeroing.
//   blocks [0, 4096):      grn row (c,i): y, y2 (fp32), A_S row -> bf16, swizzled
//   blocks [4096, 4160):   baseline epi for all genes (s=z, s2=1)
//   blocks [4160, 4176):   zero the 128 KB tagged-pair exchange buffer
// ============================================================================
__global__ __launch_bounds__(256) void prep_kernel(
    const float* __restrict__ z, const float* __restrict__ grn,
    const int* __restrict__ tf,
    const float* __restrict__ wz, const float* __restrict__ bz,
    const float* __restrict__ w1, const float* __restrict__ b1,
    const float* __restrict__ w2, const float* __restrict__ b2,
    float* __restrict__ out,
    unsigned int* __restrict__ A2, float* __restrict__ y, float* __restrict__ y2,
    unsigned long long* __restrict__ pairs)
{
    const int b   = blockIdx.x;
    const int tid = threadIdx.x;

    if (b < CC * TFN) {
        // ---------------- grn row path ----------------
        __shared__ float row[TGN];
        __shared__ int   tfs[TFN];
        __shared__ float red[8];
        const int c = b >> 9;

        const float4* g4 = (const float4*)(grn + (size_t)b * TGN);
        const float4* z4 = (const float4*)(z + c * TGN);
        float4* r4 = (float4*)row;

        float accy = 0.f, accs = 0.f;
        for (int k = tid; k < TGN / 4; k += 256) {
            float4 g = g4[k];
            float4 zz = z4[k];
            r4[k] = g;
            accy += g.x * zz.x + g.y * zz.y + g.z * zz.z + g.w * zz.w;
            accs += g.x + g.y + g.z + g.w;
        }
        for (int k = tid; k < TFN; k += 256) {
            int t = tf[c * TFN + k];
            tfs[k] = t < 0 ? 0 : (t >= TGN ? TGN - 1 : t);
        }
        for (int off = 32; off > 0; off >>= 1) {
            accy += __shfl_down(accy, off);
            accs += __shfl_down(accs, off);
        }
        const int wave = tid >> 6, lane = tid & 63;
        if (lane == 0) { red[wave] = accy; red[4 + wave] = accs; }
        __syncthreads();
        if (tid == 0) {
            y[b]  = red[0] + red[1] + red[2] + red[3];
            y2[b] = red[4] + red[5] + red[6] + red[7];
        }
        // A_S row -> bf16, swizzled: i_row=b&511; q=i_row>>7; r=i_row&127
        // dword d (cols 2d,2d+1): off = (c*4+q)*32768 + (d>>3)*1024 + r*8 + (d&7)
        const int i_row = b & 511;
        const int q = i_row >> 7, r = i_row & 127;
        const size_t base = (size_t)(c * 4 + q) * 32768 + r * 8;
        const int d = tid;
        unsigned int lo = f2bf(row[tfs[2 * d]]);
        unsigned int hi = f2bf(row[tfs[2 * d + 1]]);
        A2[base + (size_t)(d >> 3) * 1024 + (d & 7)] = lo | (hi << 16);
    } else if (b < CC * TFN + 64) {
        // ---------------- baseline epi (all genes) ----------------
        __shared__ float sv1[HN], su1[HN], sb1[HN], sw20[HN], sw21[HN], sb2v[2];
        if (tid < HN) {
            float a = 0.f, bb = 0.f;
            const float4* w14 = (const float4*)(w1 + tid * HN);
            const float4* wz4 = (const float4*)wz;
            const float4* bz4 = (const float4*)bz;
#pragma unroll
            for (int h4 = 0; h4 < HN / 4; ++h4) {
                float4 w = w14[h4], a4 = wz4[h4], b4 = bz4[h4];
                a  += w.x * a4.x + w.y * a4.y + w.z * a4.z + w.w * a4.w;
                bb += w.x * b4.x + w.y * b4.y + w.z * b4.z + w.w * b4.w;
            }
            sv1[tid] = a; su1[tid] = bb;
            sb1[tid] = b1[tid]; sw20[tid] = w2[tid]; sw21[tid] = w2[HN + tid];
            if (tid < 2) sb2v[tid] = b2[tid];
        }
        __syncthreads();
        const int gid = (b - CC * TFN) * 256 + tid;   // 0..16383
        const float s = z[gid];
        float a0 = 0.f, a1 = 0.f;
#pragma unroll
        for (int o = 0; o < HN; ++o) {
            float pre = fmaf(s, sv1[o], su1[o] + sb1[o]);   // s2 = 1
            float h = fmaxf(pre, 0.f);
            a0 = fmaf(sw20[o], h, a0);
            a1 = fmaf(sw21[o], h, a1);
        }
        const float mu = a0 + sb2v[0];
        const float x  = a1 + sb2v[1];
        const float sp = fmaxf(x, 0.f) + log1pf(expf(-fabsf(x)));
        out[gid]            = mu;
        out[CC * TGN + gid] = sp + 1e-6f;
    } else {
        // zero tagged-pair exchange buffer: 2 parities x 8 cond x 1024 u64
        const int zi = b - (CC * TFN + 64);           // 0..15
        unsigned long long* p = pairs + (size_t)zi * 1024;
        for (int k = tid; k < 1024; k += 256) p[k] = 0ULL;
    }
}

// ============================================================================
// K2: Neumann solve (A_S bf16 in registers, 4 blocks/condition) + TF-gene epi.
// Cross-block exchange: each float is published as a tagged u64
// (iter<<32 | float_bits) via relaxed agent atomic store; consumers poll
// DIRECTLY on their own data word with fetch_add(0) u64 RMW (always reads the
// true LLC value). One LLC round trip per sync; no flags, no second pass.
// Slots are parity-double-buffered (reuse only 2 iterations later - safe).
// ============================================================================
__global__ __launch_bounds__(1024) void solve_kernel(
    const float* __restrict__ z, const int* __restrict__ tf,
    const float* __restrict__ wz, const float* __restrict__ bz,
    const float* __restrict__ w1, const float* __restrict__ b1,
    const float* __restrict__ w2, const float* __restrict__ b2,
    float* __restrict__ out,
    const unsigned int* __restrict__ A2,
    const float* __restrict__ y, const float* __restrict__ y2,
    unsigned long long* __restrict__ pairs)
{
    __shared__ float y_lds[2 * TFN];
    __shared__ float w_lds[2 * TFN];
    __shared__ float sv1[HN], su1[HN], sb1[HN], sw20[HN], sw21[HN], sb2v[2];
    __shared__ int   tfs_own[128];
    __shared__ float sS[128], sS2[128];

    const int b = blockIdx.x;
    const int c = b >> 2, q = b & 3;
    const int t = threadIdx.x;
    const int r = t >> 3, cb = t & 7;
    const int row0 = q * 128;

    // A slice -> registers: areg[i] holds cols {2(cb+8i), 2(cb+8i)+1} of row (row0+r)
    unsigned int areg[32];
    const unsigned int* Ab = A2 + (size_t)(c * 4 + q) * 32768 + r * 8 + cb;
#pragma unroll
    for (int i = 0; i < 32; ++i) areg[i] = Ab[(size_t)i * 1024];

    if (t < TFN) y_lds[t] = y[c * TFN + t];
    else         y_lds[t] = y2[c * TFN + (t - TFN)];
    if (t < HN) {
        float a = 0.f, bb = 0.f;
        const float4* w14 = (const float4*)(w1 + t * HN);
        const float4* wz4 = (const float4*)wz;
        const float4* bz4 = (const float4*)bz;
#pragma unroll
        for (int h4 = 0; h4 < HN / 4; ++h4) {
            float4 w = w14[h4], a4 = wz4[h4], b4 = bz4[h4];
            a  += w.x * a4.x + w.y * a4.y + w.z * a4.z + w.w * a4.w;
            bb += w.x * b4.x + w.y * b4.y + w.z * b4.z + w.w * b4.w;
        }
        sv1[t] = a; su1[t] = bb;
        sb1[t] = b1[t]; sw20[t] = w2[t]; sw21[t] = w2[HN + t];
        if (t < 2) sb2v[t] = b2[t];
    }
    if (t < 128) {
        int v = tf[c * TFN + row0 + t];
        tfs_own[t] = v < 0 ? 0 : (v >= TGN ? TGN - 1 : v);
    }
    __syncthreads();

    const float myY  = y_lds[row0 + r];
    const float myY2 = y_lds[TFN + row0 + r];

    float wv = 0.f, w2v = 0.f;   // own-chunk result (valid in cb==0 lanes)

    for (int it = 1; it <= NITER; ++it) {
        const float* src = (it == 1) ? y_lds : w_lds;
        float a1 = 0.f, a2 = 0.f;
#pragma unroll
        for (int i = 0; i < 32; ++i) {
            unsigned int ad = areg[i];
            float alo = __uint_as_float(ad << 16);
            float ahi = __uint_as_float(ad & 0xffff0000u);
            int j = 2 * (cb + 8 * i);
            a1 = fmaf(alo, src[j],           a1);
            a1 = fmaf(ahi, src[j + 1],       a1);
            a2 = fmaf(alo, src[TFN + j],     a2);
            a2 = fmaf(ahi, src[TFN + j + 1], a2);
        }
        a1 += __shfl_down(a1, 4, 8); a1 += __shfl_down(a1, 2, 8); a1 += __shfl_down(a1, 1, 8);
        a2 += __shfl_down(a2, 4, 8); a2 += __shfl_down(a2, 2, 8); a2 += __shfl_down(a2, 1, 8);
        if (cb == 0) { wv = myY + a1; w2v = myY2 + a2; }

        if (it < NITER) {
            unsigned long long* pb = pairs + (size_t)(it & 1) * (CC * 1024) + c * 1024;
            if (cb == 0) {
                const unsigned long long tag = (unsigned long long)(unsigned int)it << 32;
                __hip_atomic_store(&pb[row0 + r],
                                   tag | (unsigned long long)__float_as_uint(wv),
                                   __ATOMIC_RELAXED, __HIP_MEMORY_SCOPE_AGENT);
                __hip_atomic_store(&pb[TFN + row0 + r],
                                   tag | (unsigned long long)__float_as_uint(w2v),
                                   __ATOMIC_RELAXED, __HIP_MEMORY_SCOPE_AGENT);
            }
            __syncthreads();   // vmcnt(0) drain -> own stores completed at LLC
            // fused poll: RMW my own data word until its tag matches this iter
            unsigned long long v;
            int polls = 0;
            for (;;) {
                v = __hip_atomic_fetch_add(&pb[t], 0ULL,
                                           __ATOMIC_RELAXED, __HIP_MEMORY_SCOPE_AGENT);
                if ((unsigned int)(v >> 32) == (unsigned int)it) break;
                __builtin_amdgcn_s_sleep(1);
                if (++polls > (1 << 22)) break;
            }
            w_lds[t] = __uint_as_float((unsigned int)v);
            __syncthreads();
        }
    }

    // ---- TF-gene epilogue (own 128 rows) ----
    if (cb == 0) {
        int g = tfs_own[r];
        sS[r]  = z[c * TGN + g] + wv;
        sS2[r] = 1.f + w2v;
    }
    __syncthreads();
    const float s = sS[r], s2 = sS2[r];
    float a0 = 0.f, a1e = 0.f;
#pragma unroll
    for (int oo = 0; oo < 8; ++oo) {
        int o = cb * 8 + oo;
        float pre = fmaf(s, sv1[o], fmaf(s2, su1[o], sb1[o]));
        float h = fmaxf(pre, 0.f);
        a0  = fmaf(sw20[o], h, a0);
        a1e = fmaf(sw21[o], h, a1e);
    }
    a0  += __shfl_down(a0, 4, 8);  a0  += __shfl_down(a0, 2, 8);  a0  += __shfl_down(a0, 1, 8);
    a1e += __shfl_down(a1e, 4, 8); a1e += __shfl_down(a1e, 2, 8); a1e += __shfl_down(a1e, 1, 8);
    if (cb == 0) {
        int g = tfs_own[r];
        float mu = a0 + sb2v[0];
        float x  = a1e + sb2v[1];
        float sp = fmaxf(x, 0.f) + log1pf(expf(-fabsf(x)));
        out[c * TGN + g]            = mu;
        out[CC * TGN + c * TGN + g] = sp + 1e-6f;
    }
}

extern "C" void kernel_launch(void* const* d_in, const int* in_sizes, int n_in,
                              void* d_out, int out_size, void* d_ws, size_t ws_size,
                              hipStream_t stream)
{
    const float* z   = (const float*)d_in[0];
    const float* grn = (const float*)d_in[1];
    const int*   tf  = (const int*)d_in[2];
    const float* wz  = (const float*)d_in[4];
    const float* bz  = (const float*)d_in[5];
    const float* w1  = (const float*)d_in[6];
    const float* b1  = (const float*)d_in[7];
    const float* w2  = (const float*)d_in[8];
    const float* b2  = (const float*)d_in[9];
    float* out = (float*)d_out;

    char* ws = (char*)d_ws;
    unsigned int* A2 = (unsigned int*)ws;              // 4 MB (bf16 A_S, swizzled)
    float* y    = (float*)(ws + 4194304);
    float* y2   = (float*)(ws + 4210688);
    unsigned long long* pairs = (unsigned long long*)(ws + 4227072);  // 128 KB

    prep_kernel<<<CC * TFN + 64 + 16, 256, 0, stream>>>(
        z, grn, tf, wz, bz, w1, b1, w2, b2, out, A2, y, y2, pairs);

    solve_kernel<<<32, 1024, 0, stream>>>(
        z, tf, wz, bz, w1, b1, w2, b2, out, A2, y, y2, pairs);
}

// Round 8
// 28.015 us; speedup vs baseline: 26.8362x; 1.2311x over previous
//
#include <hip/hip_runtime.h>
#include <math.h>

#define CC    8
#define TFN   512
#define TGN   2048
#define HN    64
#define NITER 3
#define QB    8      // solve blocks per condition
#define RB    64     // rows per solve block
#define TR    16     // threads per row in solve

// ---- bf16 helper (manual, RNE) ----
__device__ __forceinline__ unsigned short f2bf(float f) {
    unsigned int u = __float_as_uint(f);
    unsigned int r = (u + 0x7fffu + ((u >> 16) & 1u)) >> 16;
    return (unsigned short)r;
}

// ============================================================================
// K1: prep + baseline epilogue + pair-buffer zeroing.
//   blocks [0, 4096):      grn row (c,i): y, y2 (fp32), A_S row -> bf16,
//                          swizzled for QB=8/RB=64 solve layout
//   blocks [4096, 4160):   baseline epi for all genes (s=z, s2=1)
//   blocks [4160, 4176):   zero the 128 KB tagged-pair exchange buffer
// ============================================================================
__global__ __launch_bounds__(256) void prep_kernel(
    const float* __restrict__ z, const float* __restrict__ grn,
    const int* __restrict__ tf,
    const float* __restrict__ wz, const float* __restrict__ bz,
    const float* __restrict__ w1, const float* __restrict__ b1,
    const float* __restrict__ w2, const float* __restrict__ b2,
    float* __restrict__ out,
    unsigned int* __restrict__ A2, float* __restrict__ y, float* __restrict__ y2,
    unsigned long long* __restrict__ pairs)
{
    const int b   = blockIdx.x;
    const int tid = threadIdx.x;

    if (b < CC * TFN) {
        // ---------------- grn row path ----------------
        __shared__ float row[TGN];
        __shared__ int   tfs[TFN];
        __shared__ float red[8];
        const int c = b >> 9;

        const float4* g4 = (const float4*)(grn + (size_t)b * TGN);
        const float4* z4 = (const float4*)(z + c * TGN);
        float4* r4 = (float4*)row;

        float accy = 0.f, accs = 0.f;
        for (int k = tid; k < TGN / 4; k += 256) {
            float4 g = g4[k];
            float4 zz = z4[k];
            r4[k] = g;
            accy += g.x * zz.x + g.y * zz.y + g.z * zz.z + g.w * zz.w;
            accs += g.x + g.y + g.z + g.w;
        }
        for (int k = tid; k < TFN; k += 256) {
            int t = tf[c * TFN + k];
            tfs[k] = t < 0 ? 0 : (t >= TGN ? TGN - 1 : t);
        }
        for (int off = 32; off > 0; off >>= 1) {
            accy += __shfl_down(accy, off);
            accs += __shfl_down(accs, off);
        }
        const int wave = tid >> 6, lane = tid & 63;
        if (lane == 0) { red[wave] = accy; red[4 + wave] = accs; }
        __syncthreads();
        if (tid == 0) {
            y[b]  = red[0] + red[1] + red[2] + red[3];
            y2[b] = red[4] + red[5] + red[6] + red[7];
        }
        // A_S row -> bf16, swizzled for solve: q=i_row>>6, r=i_row&63
        // dword d (cols 2d,2d+1): off = (c*8+q)*16384 + (d>>4)*1024 + r*16 + (d&15)
        const int i_row = b & 511;
        const int q = i_row >> 6, r = i_row & 63;
        const size_t base = (size_t)(c * QB + q) * 16384 + r * 16;
        const int d = tid;
        unsigned int lo = f2bf(row[tfs[2 * d]]);
        unsigned int hi = f2bf(row[tfs[2 * d + 1]]);
        A2[base + (size_t)(d >> 4) * 1024 + (d & 15)] = lo | (hi << 16);
    } else if (b < CC * TFN + 64) {
        // ---------------- baseline epi (all genes) ----------------
        __shared__ float sv1[HN], su1[HN], sb1[HN], sw20[HN], sw21[HN], sb2v[2];
        if (tid < HN) {
            float a = 0.f, bb = 0.f;
            const float4* w14 = (const float4*)(w1 + tid * HN);
            const float4* wz4 = (const float4*)wz;
            const float4* bz4 = (const float4*)bz;
#pragma unroll
            for (int h4 = 0; h4 < HN / 4; ++h4) {
                float4 w = w14[h4], a4 = wz4[h4], b4 = bz4[h4];
                a  += w.x * a4.x + w.y * a4.y + w.z * a4.z + w.w * a4.w;
                bb += w.x * b4.x + w.y * b4.y + w.z * b4.z + w.w * b4.w;
            }
            sv1[tid] = a; su1[tid] = bb;
            sb1[tid] = b1[tid]; sw20[tid] = w2[tid]; sw21[tid] = w2[HN + tid];
            if (tid < 2) sb2v[tid] = b2[tid];
        }
        __syncthreads();
        const int gid = (b - CC * TFN) * 256 + tid;   // 0..16383
        const float s = z[gid];
        float a0 = 0.f, a1 = 0.f;
#pragma unroll
        for (int o = 0; o < HN; ++o) {
            float pre = fmaf(s, sv1[o], su1[o] + sb1[o]);   // s2 = 1
            float h = fmaxf(pre, 0.f);
            a0 = fmaf(sw20[o], h, a0);
            a1 = fmaf(sw21[o], h, a1);
        }
        const float mu = a0 + sb2v[0];
        const float x  = a1 + sb2v[1];
        const float sp = fmaxf(x, 0.f) + log1pf(expf(-fabsf(x)));
        out[gid]            = mu;
        out[CC * TGN + gid] = sp + 1e-6f;
    } else {
        // zero tagged-pair exchange buffer: 2 parities x 8 cond x 1024 u64
        const int zi = b - (CC * TFN + 64);           // 0..15
        unsigned long long* p = pairs + (size_t)zi * 1024;
        for (int k = tid; k < 1024; k += 256) p[k] = 0ULL;
    }
}

// ============================================================================
// K2: Neumann solve, 8 blocks/condition (64 rows each, A_S bf16 in registers)
// + TF-gene epilogue. Dual-RHS (b_z) path is gated on a runtime-uniform
// has2 flag (b_z==0 in this problem -> skipped). Cross-block exchange via
// tagged u64 relaxed-atomic publish + fetch_add(0) RMW poll on own word.
// NITER=3 -> 2 syncs; parity slots each used once per call.
// ============================================================================
__global__ __launch_bounds__(1024) void solve_kernel(
    const float* __restrict__ z, const int* __restrict__ tf,
    const float* __restrict__ wz, const float* __restrict__ bz,
    const float* __restrict__ w1, const float* __restrict__ b1,
    const float* __restrict__ w2, const float* __restrict__ b2,
    float* __restrict__ out,
    const unsigned int* __restrict__ A2,
    const float* __restrict__ y, const float* __restrict__ y2,
    unsigned long long* __restrict__ pairs)
{
    __shared__ float w_lds[TFN];
    __shared__ float w2_lds[TFN];
    __shared__ float sv1[HN], su1[HN], sb1[HN], sw20[HN], sw21[HN], sb2v[2];
    __shared__ int   tfs_own[RB];
    __shared__ float sS[RB], sS2[RB];
    __shared__ unsigned int snz;

    const int b = blockIdx.x;
    const int c = b >> 3, q = b & 7;
    const int t = threadIdx.x;
    const int r = t >> 4, cb = t & 15;    // 64 rows x 16 threads/row
    const int row0 = q * RB;

    if (t == 0) snz = 0u;

    // A slice -> registers: areg[i] = cols {2(cb+16i), 2(cb+16i)+1} of row row0+r
    unsigned int areg[16];
    const unsigned int* Ab = A2 + (size_t)(c * QB + q) * 16384 + r * 16 + cb;
#pragma unroll
    for (int i = 0; i < 16; ++i) areg[i] = Ab[(size_t)i * 1024];

    if (t < TFN) {
        w_lds[t]  = y[c * TFN + t];
        w2_lds[t] = y2[c * TFN + t];
    }
    if (t < HN) {
        float a = 0.f, bb = 0.f;
        const float4* w14 = (const float4*)(w1 + t * HN);
        const float4* wz4 = (const float4*)wz;
        const float4* bz4 = (const float4*)bz;
#pragma unroll
        for (int h4 = 0; h4 < HN / 4; ++h4) {
            float4 w = w14[h4], a4 = wz4[h4], b4 = bz4[h4];
            a  += w.x * a4.x + w.y * a4.y + w.z * a4.z + w.w * a4.w;
            bb += w.x * b4.x + w.y * b4.y + w.z * b4.z + w.w * b4.w;
        }
        sv1[t] = a; su1[t] = bb;
        sb1[t] = b1[t]; sw20[t] = w2[t]; sw21[t] = w2[HN + t];
        if (t < 2) sb2v[t] = b2[t];
        if (bz[t] != 0.f) atomicOr(&snz, 1u);
    }
    if (t < RB) {
        int v = tf[c * TFN + row0 + t];
        tfs_own[t] = v < 0 ? 0 : (v >= TGN ? TGN - 1 : v);
    }
    __syncthreads();

    const bool has2 = (snz != 0u);
    const float myY  = w_lds[row0 + r];
    const float myY2 = w2_lds[row0 + r];

    float wv = 0.f, w2v = 0.f;   // valid in cb==0 lanes

    for (int it = 1; it <= NITER; ++it) {
        float a1 = 0.f, a2 = 0.f;
        if (has2) {
#pragma unroll
            for (int i = 0; i < 16; ++i) {
                unsigned int ad = areg[i];
                float alo = __uint_as_float(ad << 16);
                float ahi = __uint_as_float(ad & 0xffff0000u);
                float2 wp = *(const float2*)&w_lds[2 * (cb + 16 * i)];
                float2 wq = *(const float2*)&w2_lds[2 * (cb + 16 * i)];
                a1 = fmaf(alo, wp.x, a1);
                a1 = fmaf(ahi, wp.y, a1);
                a2 = fmaf(alo, wq.x, a2);
                a2 = fmaf(ahi, wq.y, a2);
            }
        } else {
#pragma unroll
            for (int i = 0; i < 16; ++i) {
                unsigned int ad = areg[i];
                float alo = __uint_as_float(ad << 16);
                float ahi = __uint_as_float(ad & 0xffff0000u);
                float2 wp = *(const float2*)&w_lds[2 * (cb + 16 * i)];
                a1 = fmaf(alo, wp.x, a1);
                a1 = fmaf(ahi, wp.y, a1);
            }
        }
        a1 += __shfl_down(a1, 8, 16); a1 += __shfl_down(a1, 4, 16);
        a1 += __shfl_down(a1, 2, 16); a1 += __shfl_down(a1, 1, 16);
        if (has2) {
            a2 += __shfl_down(a2, 8, 16); a2 += __shfl_down(a2, 4, 16);
            a2 += __shfl_down(a2, 2, 16); a2 += __shfl_down(a2, 1, 16);
        }
        if (cb == 0) {
            wv = myY + a1;
            if (has2) w2v = myY2 + a2;
        }

        if (it < NITER) {
            unsigned long long* pb = pairs + (size_t)(it & 1) * (CC * 1024) + c * 1024;
            const unsigned long long tag = (unsigned long long)(unsigned int)it << 32;
            if (cb == 0) {
                __hip_atomic_store(&pb[row0 + r],
                                   tag | (unsigned long long)__float_as_uint(wv),
                                   __ATOMIC_RELAXED, __HIP_MEMORY_SCOPE_AGENT);
                if (has2)
                    __hip_atomic_store(&pb[TFN + row0 + r],
                                       tag | (unsigned long long)__float_as_uint(w2v),
                                       __ATOMIC_RELAXED, __HIP_MEMORY_SCOPE_AGENT);
            }
            // fused poll: RMW own data word until its tag matches this iter
            if (t < TFN) {
                unsigned long long v;
                int polls = 0;
                for (;;) {
                    v = __hip_atomic_fetch_add(&pb[t], 0ULL,
                                               __ATOMIC_RELAXED, __HIP_MEMORY_SCOPE_AGENT);
                    if ((unsigned int)(v >> 32) == (unsigned int)it) break;
                    __builtin_amdgcn_s_sleep(1);
                    if (++polls > (1 << 22)) break;
                }
                w_lds[t] = __uint_as_float((unsigned int)v);
            } else if (has2) {
                unsigned long long v;
                int polls = 0;
                for (;;) {
                    v = __hip_atomic_fetch_add(&pb[t], 0ULL,
                                               __ATOMIC_RELAXED, __HIP_MEMORY_SCOPE_AGENT);
                    if ((unsigned int)(v >> 32) == (unsigned int)it) break;
                    __builtin_amdgcn_s_sleep(1);
                    if (++polls > (1 << 22)) break;
                }
                w2_lds[t - TFN] = __uint_as_float((unsigned int)v);
            }
            __syncthreads();
        }
    }

    // ---- TF-gene epilogue (own 64 rows; 16 threads/gene, 4 h-outputs each) ----
    if (cb == 0) {
        int g = tfs_own[r];
        sS[r]  = z[c * TGN + g] + wv;
        sS2[r] = has2 ? (1.f + w2v) : 1.f;
    }
    __syncthreads();
    const float s = sS[r], s2 = sS2[r];
    float a0 = 0.f, a1e = 0.f;
#pragma unroll
    for (int oo = 0; oo < 4; ++oo) {
        int o = cb * 4 + oo;
        float pre = fmaf(s, sv1[o], fmaf(s2, su1[o], sb1[o]));
        float h = fmaxf(pre, 0.f);
        a0  = fmaf(sw20[o], h, a0);
        a1e = fmaf(sw21[o], h, a1e);
    }
    a0  += __shfl_down(a0, 8, 16);  a0  += __shfl_down(a0, 4, 16);
    a0  += __shfl_down(a0, 2, 16);  a0  += __shfl_down(a0, 1, 16);
    a1e += __shfl_down(a1e, 8, 16); a1e += __shfl_down(a1e, 4, 16);
    a1e += __shfl_down(a1e, 2, 16); a1e += __shfl_down(a1e, 1, 16);
    if (cb == 0) {
        int g = tfs_own[r];
        float mu = a0 + sb2v[0];
        float x  = a1e + sb2v[1];
        float sp = fmaxf(x, 0.f) + log1pf(expf(-fabsf(x)));
        out[c * TGN + g]            = mu;
        out[CC * TGN + c * TGN + g] = sp + 1e-6f;
    }
}

extern "C" void kernel_launch(void* const* d_in, const int* in_sizes, int n_in,
                              void* d_out, int out_size, void* d_ws, size_t ws_size,
                              hipStream_t stream)
{
    const float* z   = (const float*)d_in[0];
    const float* grn = (const float*)d_in[1];
    const int*   tf  = (const int*)d_in[2];
    const float* wz  = (const float*)d_in[4];
    const float* bz  = (const float*)d_in[5];
    const float* w1  = (const float*)d_in[6];
    const float* b1  = (const float*)d_in[7];
    const float* w2  = (const float*)d_in[8];
    const float* b2  = (const float*)d_in[9];
    float* out = (float*)d_out;

    char* ws = (char*)d_ws;
    unsigned int* A2 = (unsigned int*)ws;              // 4 MB (bf16 A_S, swizzled)
    float* y    = (float*)(ws + 4194304);
    float* y2   = (float*)(ws + 4210688);
    unsigned long long* pairs = (unsigned long long*)(ws + 4227072);  // 128 KB

    prep_kernel<<<CC * TFN + 64 + 16, 256, 0, stream>>>(
        z, grn, tf, wz, bz, w1, b1, w2, b2, out, A2, y, y2, pairs);

    solve_kernel<<<CC * QB, 1024, 0, stream>>>(
        z, tf, wz, bz, w1, b1, w2, b2, out, A2, y, y2, pairs);
}

// Round 9
// 25.593 us; speedup vs baseline: 29.3759x; 1.0946x over previous
//
#include <hip/hip_runtime.h>
#include <math.h>

#define CC    8
#define TFN   512
#define TGN   2048
#define HN    64
#define NITER 2
#define QB    8      // solve blocks per condition
#define RB    64     // rows per solve block

// ---- bf16 helper (manual, RNE) ----
__device__ __forceinline__ unsigned short f2bf(float f) {
    unsigned int u = __float_as_uint(f);
    unsigned int r = (u + 0x7fffu + ((u >> 16) & 1u)) >> 16;
    return (unsigned short)r;
}

// ============================================================================
// K1: prep + baseline epilogue + counter zeroing.
//   blocks [0, 4096):      grn row (c,i): y, y2 (fp32), A_S row -> bf16,
//                          swizzled for QB=8/RB=64 solve layout
//   blocks [4096, 4160):   baseline epi for all genes (s=z, s2=1)
//   block  4160:           zero the 8 per-condition sync counters
// ============================================================================
__global__ __launch_bounds__(256) void prep_kernel(
    const float* __restrict__ z, const float* __restrict__ grn,
    const int* __restrict__ tf,
    const float* __restrict__ wz, const float* __restrict__ bz,
    const float* __restrict__ w1, const float* __restrict__ b1,
    const float* __restrict__ w2, const float* __restrict__ b2,
    float* __restrict__ out,
    unsigned int* __restrict__ A2, float* __restrict__ y, float* __restrict__ y2,
    unsigned int* __restrict__ cnt)
{
    const int b   = blockIdx.x;
    const int tid = threadIdx.x;

    if (b < CC * TFN) {
        // ---------------- grn row path ----------------
        __shared__ float row[TGN];
        __shared__ int   tfs[TFN];
        __shared__ float red[8];
        const int c = b >> 9;

        const float4* g4 = (const float4*)(grn + (size_t)b * TGN);
        const float4* z4 = (const float4*)(z + c * TGN);
        float4* r4 = (float4*)row;

        float accy = 0.f, accs = 0.f;
        for (int k = tid; k < TGN / 4; k += 256) {
            float4 g = g4[k];
            float4 zz = z4[k];
            r4[k] = g;
            accy += g.x * zz.x + g.y * zz.y + g.z * zz.z + g.w * zz.w;
            accs += g.x + g.y + g.z + g.w;
        }
        for (int k = tid; k < TFN; k += 256) {
            int t = tf[c * TFN + k];
            tfs[k] = t < 0 ? 0 : (t >= TGN ? TGN - 1 : t);
        }
        for (int off = 32; off > 0; off >>= 1) {
            accy += __shfl_down(accy, off);
            accs += __shfl_down(accs, off);
        }
        const int wave = tid >> 6, lane = tid & 63;
        if (lane == 0) { red[wave] = accy; red[4 + wave] = accs; }
        __syncthreads();
        if (tid == 0) {
            y[b]  = red[0] + red[1] + red[2] + red[3];
            y2[b] = red[4] + red[5] + red[6] + red[7];
        }
        // A_S row -> bf16, swizzled for solve: q=i_row>>6, r=i_row&63
        // dword d (cols 2d,2d+1): off = (c*8+q)*16384 + (d>>4)*1024 + r*16 + (d&15)
        const int i_row = b & 511;
        const int q = i_row >> 6, r = i_row & 63;
        const size_t base = (size_t)(c * QB + q) * 16384 + r * 16;
        const int d = tid;
        unsigned int lo = f2bf(row[tfs[2 * d]]);
        unsigned int hi = f2bf(row[tfs[2 * d + 1]]);
        A2[base + (size_t)(d >> 4) * 1024 + (d & 15)] = lo | (hi << 16);
    } else if (b < CC * TFN + 64) {
        // ---------------- baseline epi (all genes) ----------------
        __shared__ float sv1[HN], su1[HN], sb1[HN], sw20[HN], sw21[HN], sb2v[2];
        if (tid < HN) {
            float a = 0.f, bb = 0.f;
            const float4* w14 = (const float4*)(w1 + tid * HN);
            const float4* wz4 = (const float4*)wz;
            const float4* bz4 = (const float4*)bz;
#pragma unroll
            for (int h4 = 0; h4 < HN / 4; ++h4) {
                float4 w = w14[h4], a4 = wz4[h4], b4 = bz4[h4];
                a  += w.x * a4.x + w.y * a4.y + w.z * a4.z + w.w * a4.w;
                bb += w.x * b4.x + w.y * b4.y + w.z * b4.z + w.w * b4.w;
            }
            sv1[tid] = a; su1[tid] = bb;
            sb1[tid] = b1[tid]; sw20[tid] = w2[tid]; sw21[tid] = w2[HN + tid];
            if (tid < 2) sb2v[tid] = b2[tid];
        }
        __syncthreads();
        const int gid = (b - CC * TFN) * 256 + tid;   // 0..16383
        const float s = z[gid];
        float a0 = 0.f, a1 = 0.f;
#pragma unroll
        for (int o = 0; o < HN; ++o) {
            float pre = fmaf(s, sv1[o], su1[o] + sb1[o]);   // s2 = 1
            float h = fmaxf(pre, 0.f);
            a0 = fmaf(sw20[o], h, a0);
            a1 = fmaf(sw21[o], h, a1);
        }
        const float mu = a0 + sb2v[0];
        const float x  = a1 + sb2v[1];
        const float sp = fmaxf(x, 0.f) + log1pf(expf(-fabsf(x)));
        out[gid]            = mu;
        out[CC * TGN + gid] = sp + 1e-6f;
    } else {
        // zero per-condition counters (8 counters, 64B apart)
        if (tid < 128)
            __hip_atomic_store(&cnt[tid], 0u, __ATOMIC_RELAXED, __HIP_MEMORY_SCOPE_AGENT);
    }
}

// ============================================================================
// K2: Neumann solve (NITER=2 -> ONE cross-block sync), 8 blocks/condition,
// A_S bf16 in registers. Sync protocol (uncongested):
//   producers: relaxed atomic stores of w -> __syncthreads (vmcnt drain)
//              -> one fetch_add(+1) on the condition counter
//   consumer:  ONE poller thread per block RMW-polls counter==8
//              -> __syncthreads -> bulk relaxed atomic loads of w.
// Dual-RHS (b_z) path gated by ballot-computed has2 (b_z==0 here -> skipped).
// ============================================================================
__global__ __launch_bounds__(1024) void solve_kernel(
    const float* __restrict__ z, const int* __restrict__ tf,
    const float* __restrict__ wz, const float* __restrict__ bz,
    const float* __restrict__ w1, const float* __restrict__ b1,
    const float* __restrict__ w2, const float* __restrict__ b2,
    float* __restrict__ out,
    const unsigned int* __restrict__ A2,
    const float* __restrict__ y, const float* __restrict__ y2,
    float* __restrict__ wX, float* __restrict__ w2X,
    unsigned int* __restrict__ cnt)
{
    __shared__ float w_lds[TFN];
    __shared__ float w2_lds[TFN];
    __shared__ float sv1[HN], su1[HN], sb1[HN], sw20[HN], sw21[HN], sb2v[2];
    __shared__ int   tfs_own[RB];
    __shared__ float sS[RB], sS2[RB];
    __shared__ unsigned int snz;

    const int b = blockIdx.x;
    const int c = b >> 3, q = b & 7;
    const int t = threadIdx.x;
    const int r = t >> 4, cb = t & 15;    // 64 rows x 16 threads/row
    const int row0 = q * RB;

    // A slice -> registers: areg[i] = cols {2(cb+16i), 2(cb+16i)+1} of row row0+r
    unsigned int areg[16];
    const unsigned int* Ab = A2 + (size_t)(c * QB + q) * 16384 + r * 16 + cb;
#pragma unroll
    for (int i = 0; i < 16; ++i) areg[i] = Ab[(size_t)i * 1024];

    if (t < TFN) {
        w_lds[t]  = y[c * TFN + t];
        w2_lds[t] = y2[c * TFN + t];
    }
    if (t < HN) {
        float a = 0.f, bb = 0.f;
        const float4* w14 = (const float4*)(w1 + t * HN);
        const float4* wz4 = (const float4*)wz;
        const float4* bz4 = (const float4*)bz;
#pragma unroll
        for (int h4 = 0; h4 < HN / 4; ++h4) {
            float4 w = w14[h4], a4 = wz4[h4], b4 = bz4[h4];
            a  += w.x * a4.x + w.y * a4.y + w.z * a4.z + w.w * a4.w;
            bb += w.x * b4.x + w.y * b4.y + w.z * b4.z + w.w * b4.w;
        }
        sv1[t] = a; su1[t] = bb;
        sb1[t] = b1[t]; sw20[t] = w2[t]; sw21[t] = w2[HN + t];
        if (t < 2) sb2v[t] = b2[t];
        // has2 via wave-0 ballot (t 0..63 are one wave): race-free single writer
        unsigned long long m = __ballot(bz[t] != 0.f);
        if (t == 0) snz = (m != 0ULL) ? 1u : 0u;
    }
    if (t < RB) {
        int v = tf[c * TFN + row0 + t];
        tfs_own[t] = v < 0 ? 0 : (v >= TGN ? TGN - 1 : v);
    }
    __syncthreads();

    const bool has2 = (snz != 0u);
    const float myY  = w_lds[row0 + r];
    const float myY2 = w2_lds[row0 + r];

    float wv = 0.f, w2v = 0.f;   // valid in cb==0 lanes

    for (int it = 1; it <= NITER; ++it) {
        float a1 = 0.f, a2 = 0.f;
        if (has2) {
#pragma unroll
            for (int i = 0; i < 16; ++i) {
                unsigned int ad = areg[i];
                float alo = __uint_as_float(ad << 16);
                float ahi = __uint_as_float(ad & 0xffff0000u);
                float2 wp = *(const float2*)&w_lds[2 * (cb + 16 * i)];
                float2 wq = *(const float2*)&w2_lds[2 * (cb + 16 * i)];
                a1 = fmaf(alo, wp.x, a1);
                a1 = fmaf(ahi, wp.y, a1);
                a2 = fmaf(alo, wq.x, a2);
                a2 = fmaf(ahi, wq.y, a2);
            }
        } else {
#pragma unroll
            for (int i = 0; i < 16; ++i) {
                unsigned int ad = areg[i];
                float alo = __uint_as_float(ad << 16);
                float ahi = __uint_as_float(ad & 0xffff0000u);
                float2 wp = *(const float2*)&w_lds[2 * (cb + 16 * i)];
                a1 = fmaf(alo, wp.x, a1);
                a1 = fmaf(ahi, wp.y, a1);
            }
        }
        a1 += __shfl_down(a1, 8, 16); a1 += __shfl_down(a1, 4, 16);
        a1 += __shfl_down(a1, 2, 16); a1 += __shfl_down(a1, 1, 16);
        if (has2) {
            a2 += __shfl_down(a2, 8, 16); a2 += __shfl_down(a2, 4, 16);
            a2 += __shfl_down(a2, 2, 16); a2 += __shfl_down(a2, 1, 16);
        }
        if (cb == 0) {
            wv = myY + a1;
            if (has2) w2v = myY2 + a2;
        }

        if (it < NITER) {
            // ---- publish own 64 w values (LLC-resident atomics) ----
            if (cb == 0) {
                __hip_atomic_store(&wX[c * TFN + row0 + r], wv,
                                   __ATOMIC_RELAXED, __HIP_MEMORY_SCOPE_AGENT);
                if (has2)
                    __hip_atomic_store(&w2X[c * TFN + row0 + r], w2v,
                                       __ATOMIC_RELAXED, __HIP_MEMORY_SCOPE_AGENT);
            }
            __syncthreads();   // vmcnt(0) drain -> stores completed at LLC
            // ---- counter: one +1 per block, one poller per block ----
            if (t == 0) {
                unsigned int* pc = &cnt[c * 16];
                __hip_atomic_fetch_add(pc, 1u, __ATOMIC_RELAXED, __HIP_MEMORY_SCOPE_AGENT);
                int polls = 0;
                while (__hip_atomic_fetch_add(pc, 0u, __ATOMIC_RELAXED,
                                              __HIP_MEMORY_SCOPE_AGENT) < (unsigned int)QB) {
                    __builtin_amdgcn_s_sleep(1);
                    if (++polls > (1 << 22)) break;
                }
            }
            __syncthreads();
            // ---- bulk re-read of the full w vector ----
            if (t < TFN)
                w_lds[t] = __hip_atomic_load(&wX[c * TFN + t],
                                             __ATOMIC_RELAXED, __HIP_MEMORY_SCOPE_AGENT);
            else if (has2)
                w2_lds[t - TFN] = __hip_atomic_load(&w2X[c * TFN + (t - TFN)],
                                                    __ATOMIC_RELAXED, __HIP_MEMORY_SCOPE_AGENT);
            __syncthreads();
        }
    }

    // ---- TF-gene epilogue (own 64 rows; 16 threads/gene, 4 h-outputs each) ----
    if (cb == 0) {
        int g = tfs_own[r];
        sS[r]  = z[c * TGN + g] + wv;
        sS2[r] = has2 ? (1.f + w2v) : 1.f;
    }
    __syncthreads();
    const float s = sS[r], s2 = sS2[r];
    float a0 = 0.f, a1e = 0.f;
#pragma unroll
    for (int oo = 0; oo < 4; ++oo) {
        int o = cb * 4 + oo;
        float pre = fmaf(s, sv1[o], fmaf(s2, su1[o], sb1[o]));
        float h = fmaxf(pre, 0.f);
        a0  = fmaf(sw20[o], h, a0);
        a1e = fmaf(sw21[o], h, a1e);
    }
    a0  += __shfl_down(a0, 8, 16);  a0  += __shfl_down(a0, 4, 16);
    a0  += __shfl_down(a0, 2, 16);  a0  += __shfl_down(a0, 1, 16);
    a1e += __shfl_down(a1e, 8, 16); a1e += __shfl_down(a1e, 4, 16);
    a1e += __shfl_down(a1e, 2, 16); a1e += __shfl_down(a1e, 1, 16);
    if (cb == 0) {
        int g = tfs_own[r];
        float mu = a0 + sb2v[0];
        float x  = a1e + sb2v[1];
        float sp = fmaxf(x, 0.f) + log1pf(expf(-fabsf(x)));
        out[c * TGN + g]            = mu;
        out[CC * TGN + c * TGN + g] = sp + 1e-6f;
    }
}

extern "C" void kernel_launch(void* const* d_in, const int* in_sizes, int n_in,
                              void* d_out, int out_size, void* d_ws, size_t ws_size,
                              hipStream_t stream)
{
    const float* z   = (const float*)d_in[0];
    const float* grn = (const float*)d_in[1];
    const int*   tf  = (const int*)d_in[2];
    const float* wz  = (const float*)d_in[4];
    const float* bz  = (const float*)d_in[5];
    const float* w1  = (const float*)d_in[6];
    const float* b1  = (const float*)d_in[7];
    const float* w2  = (const float*)d_in[8];
    const float* b2  = (const float*)d_in[9];
    float* out = (float*)d_out;

    char* ws = (char*)d_ws;
    unsigned int* A2 = (unsigned int*)ws;              // 4 MB (bf16 A_S, swizzled)
    float* y    = (float*)(ws + 4194304);
    float* y2   = (float*)(ws + 4210688);
    float* wX   = (float*)(ws + 4227072);              // 16 KB exchange
    float* w2X  = (float*)(ws + 4243456);
    unsigned int* cnt = (unsigned int*)(ws + 4259840); // 8 counters, 64B apart

    prep_kernel<<<CC * TFN + 64 + 1, 256, 0, stream>>>(
        z, grn, tf, wz, bz, w1, b1, w2, b2, out, A2, y, y2, cnt);

    solve_kernel<<<CC * QB, 1024, 0, stream>>>(
        z, tf, wz, bz, w1, b1, w2, b2, out, A2, y, y2, wX, w2X, cnt);
}